// Round 2
// baseline (1985.726 us; speedup 1.0000x reference)
//
#include <hip/hip_runtime.h>
#include <hip/hip_bf16.h>

#define NTOK   8192
#define HDIM   1024
#define NEXP   8
#define IDIM   2048
#define TOTAL  (NTOK*2)

typedef short bf16x8 __attribute__((ext_vector_type(8)));
typedef float f32x4  __attribute__((ext_vector_type(4)));

__device__ __forceinline__ unsigned short f2bf(float f) {
  __hip_bfloat16 h = __float2bfloat16(f);
  return *reinterpret_cast<unsigned short*>(&h);
}
__device__ __forceinline__ float bf2f(unsigned short u) {
  __hip_bfloat16 h = *reinterpret_cast<__hip_bfloat16*>(&u);
  return __bfloat162float(h);
}

// async global->LDS, 16B per lane. LDS base must be wave-uniform; HW writes base + lane*16.
// Global source address is per-lane (this is what makes the token indirection legal).
__device__ __forceinline__ void lds_load16(const unsigned short* gsrc, unsigned short* lds_base_uniform) {
  __builtin_amdgcn_global_load_lds(
      (const __attribute__((address_space(1))) unsigned int*)gsrc,
      (__attribute__((address_space(3))) unsigned int*)lds_base_uniform,
      16, 0, 0);
}

// ---------------- router: one wave per token ----------------
__global__ void router_kernel(const float* __restrict__ x, const float* __restrict__ Wr,
                              int* __restrict__ sel, float* __restrict__ selw,
                              int* __restrict__ counts) {
  int t = blockIdx.x * 4 + (threadIdx.x >> 6);
  int lane = threadIdx.x & 63;
  float acc[NEXP];
#pragma unroll
  for (int e = 0; e < NEXP; ++e) acc[e] = 0.f;
  const float* xr = x + (size_t)t * HDIM;
  for (int h = lane; h < HDIM; h += 64) {
    float xv = xr[h];
    const float* wr = Wr + h * NEXP;
#pragma unroll
    for (int e = 0; e < NEXP; ++e) acc[e] += xv * wr[e];
  }
#pragma unroll
  for (int off = 32; off > 0; off >>= 1) {
#pragma unroll
    for (int e = 0; e < NEXP; ++e) acc[e] += __shfl_xor(acc[e], off, 64);
  }
  if (lane == 0) {
    int i0 = 0; float v0 = acc[0];
#pragma unroll
    for (int e = 1; e < NEXP; ++e) if (acc[e] > v0) { v0 = acc[e]; i0 = e; }
    int i1 = -1; float v1 = -1e30f;
#pragma unroll
    for (int e = 0; e < NEXP; ++e) if (e != i0 && acc[e] > v1) { v1 = acc[e]; i1 = e; }
    float e1 = expf(v1 - v0);
    float w0 = 1.f / (1.f + e1);
    float w1 = e1 / (1.f + e1);
    sel[t*2] = i0; sel[t*2+1] = i1;
    selw[t*2] = w0; selw[t*2+1] = w1;
    atomicAdd(&counts[i0], 1);
    atomicAdd(&counts[i1], 1);
  }
}

__global__ void prefix_kernel(const int* __restrict__ counts, int* __restrict__ offsets,
                              int* __restrict__ cursor) {
  if (threadIdx.x == 0) {
    int s = 0;
    for (int e = 0; e < NEXP; ++e) { offsets[e] = s; cursor[e] = s; s += counts[e]; }
    offsets[NEXP] = s;
  }
}

__global__ void scatter_kernel(const int* __restrict__ sel, const float* __restrict__ selw,
                               int* __restrict__ cursor, int* __restrict__ token_ids,
                               float* __restrict__ gates) {
  int t = blockIdx.x * 256 + threadIdx.x;
  if (t >= NTOK) return;
#pragma unroll
  for (int k = 0; k < 2; ++k) {
    int e = sel[t*2+k];
    int p = atomicAdd(&cursor[e], 1);
    token_ids[p] = t;
    gates[p] = selw[t*2+k];
  }
}

// x [NTOK][1024] fp32 -> Xs [NTOK][2048] bf16 (hi 0..1023 | lo 1024..2047)
__global__ void xsplit_kernel(const float* __restrict__ x, unsigned short* __restrict__ Xs) {
  int t = blockIdx.x;
  const float4* src = reinterpret_cast<const float4*>(x + (size_t)t * HDIM);
  float4 v = src[threadIdx.x];
  unsigned short h0 = f2bf(v.x), h1 = f2bf(v.y), h2 = f2bf(v.z), h3 = f2bf(v.w);
  ushort4 hi = { h0, h1, h2, h3 };
  ushort4 lo = { f2bf(v.x - bf2f(h0)), f2bf(v.y - bf2f(h1)),
                 f2bf(v.z - bf2f(h2)), f2bf(v.w - bf2f(h3)) };
  *reinterpret_cast<ushort4*>(Xs + (size_t)t*2*HDIM + threadIdx.x*4) = hi;
  *reinterpret_cast<ushort4*>(Xs + (size_t)t*2*HDIM + HDIM + threadIdx.x*4) = lo;
}

// W [E][R][C] fp32 -> WT [E][C][2R] bf16, WT[e][c][r]=hi(W[e][r][c]), WT[e][c][R+r]=lo
__global__ void split_transpose_kernel(const float* __restrict__ W, unsigned short* __restrict__ WT,
                                       int R, int C) {
  int e = blockIdx.z;
  int c0 = blockIdx.x * 64, r0 = blockIdx.y * 64;
  __shared__ unsigned short hiT[64][65];
  __shared__ unsigned short loT[64][65];
  int tx = threadIdx.x & 63, ty = threadIdx.x >> 6;
  const float* src = W + ((size_t)e * R + r0) * C + c0;
#pragma unroll
  for (int rr = 0; rr < 16; ++rr) {
    int r_l = ty * 16 + rr;
    float v = src[(size_t)r_l * C + tx];
    unsigned short h = f2bf(v);
    hiT[tx][r_l] = h;
    loT[tx][r_l] = f2bf(v - bf2f(h));
  }
  __syncthreads();
  unsigned short* dst = WT + ((size_t)e * C + c0) * (size_t)(2*R) + r0;
#pragma unroll
  for (int ww = 0; ww < 16; ++ww) {
    int c_l = ty * 16 + ww;
    dst[(size_t)c_l * (2*R) + tx]     = hiT[c_l][tx];
    dst[(size_t)c_l * (2*R) + R + tx] = loT[c_l][tx];
  }
}

// ---------------- GEMM1: act = silu(Xs@W1g) * (Xs@W1u), split-K'=3*1024 ----------------
// A rows resolved via token_ids (compact per-expert segments). actS [TOTAL][4096] (hi|lo)
__global__ __launch_bounds__(256)
void gemm1_kernel(const unsigned short* __restrict__ Xs,
                  const unsigned short* __restrict__ W1sT,
                  unsigned short* __restrict__ actS,
                  const int* __restrict__ offsets,
                  const int* __restrict__ token_ids) {
  int e = blockIdx.z;
  int off = offsets[e];
  int cnt = offsets[e+1] - off;
  int r0 = blockIdx.x * 128;
  if (r0 >= cnt) return;
  int j0 = blockIdx.y * 64;

  __shared__ unsigned short As[128*32];
  __shared__ unsigned short Bg[64*32];
  __shared__ unsigned short Bu[64*32];

  int tid = threadIdx.x;
  int lane = tid & 63, wv = tid >> 6;
  int l15 = lane & 15, lq = lane >> 4;

  f32x4 accg[2][4], accu[2][4];
#pragma unroll
  for (int m = 0; m < 2; ++m)
#pragma unroll
    for (int n = 0; n < 4; ++n) {
      accg[m][n] = f32x4{0.f, 0.f, 0.f, 0.f};
      accu[m][n] = f32x4{0.f, 0.f, 0.f, 0.f};
    }

  const unsigned short* w1e = W1sT + (size_t)e * 4096 * 2048;

  int oa0 = wv*1024 + lane*16;       // byte offset in As, issue 0
  int oa1 = 4096 + oa0;              // issue 1
  int rowA0 = oa0 >> 6, cbA0 = (oa0 & 63) >> 1;  // element offset within row
  int rowA1 = oa1 >> 6, cbA1 = (oa1 & 63) >> 1;
  int gpA0 = off + r0 + rowA0; if (gpA0 > TOTAL-1) gpA0 = TOTAL-1;
  int gpA1 = off + r0 + rowA1; if (gpA1 > TOTAL-1) gpA1 = TOTAL-1;
  int tA0 = token_ids[gpA0];
  int tA1 = token_ids[gpA1];
  const unsigned short* srcA0 = Xs + (size_t)tA0*2048 + cbA0;
  const unsigned short* srcA1 = Xs + (size_t)tA1*2048 + cbA1;
  int ob = wv*1024 + lane*16;
  int colB = ob >> 6, kbB = (ob & 63) >> 1;

  for (int ks = 0; ks < 96; ++ks) {
    int s  = ks >> 5;
    int k0 = (ks & 31) << 5;
    int acol = ((s == 1) ? HDIM : 0) + k0;   // pass1 reads A-lo
    int bk   = ((s == 2) ? HDIM : 0) + k0;   // pass2 reads B-lo

    lds_load16(srcA0 + acol, (unsigned short*)((char*)As + wv*1024));
    lds_load16(srcA1 + acol, (unsigned short*)((char*)As + 4096 + wv*1024));
    lds_load16(w1e + (size_t)(j0 + colB)*2048 + bk + kbB,        (unsigned short*)((char*)Bg + wv*1024));
    lds_load16(w1e + (size_t)(IDIM + j0 + colB)*2048 + bk + kbB, (unsigned short*)((char*)Bu + wv*1024));
    __syncthreads();

    bf16x8 af[2], bgf[4], buf2[4];
#pragma unroll
    for (int m = 0; m < 2; ++m)
      af[m] = *reinterpret_cast<const bf16x8*>(&As[(wv*32 + m*16 + l15)*32 + lq*8]);
#pragma unroll
    for (int n = 0; n < 4; ++n) {
      bgf[n]  = *reinterpret_cast<const bf16x8*>(&Bg[(n*16 + l15)*32 + lq*8]);
      buf2[n] = *reinterpret_cast<const bf16x8*>(&Bu[(n*16 + l15)*32 + lq*8]);
    }
#pragma unroll
    for (int m = 0; m < 2; ++m)
#pragma unroll
      for (int n = 0; n < 4; ++n) {
        accg[m][n] = __builtin_amdgcn_mfma_f32_16x16x32_bf16(af[m], bgf[n], accg[m][n], 0, 0, 0);
        accu[m][n] = __builtin_amdgcn_mfma_f32_16x16x32_bf16(af[m], buf2[n], accu[m][n], 0, 0, 0);
      }
    __syncthreads();
  }

#pragma unroll
  for (int m = 0; m < 2; ++m) {
#pragma unroll
    for (int rr = 0; rr < 4; ++rr) {
      int lrow = r0 + wv*32 + m*16 + lq*4 + rr;
      if (lrow < cnt) {
        size_t prow = (size_t)(off + lrow);
#pragma unroll
        for (int n = 0; n < 4; ++n) {
          float g = accg[m][n][rr], u = accu[m][n][rr];
          float a = (g / (1.f + expf(-g))) * u;   // silu(g)*u
          unsigned short hh = f2bf(a);
          unsigned short ll = f2bf(a - bf2f(hh));
          int col = j0 + n*16 + l15;
          actS[prow*4096 + col]        = hh;
          actS[prow*4096 + IDIM + col] = ll;
        }
      }
    }
  }
}

// ---------------- GEMM2: out += g * (act @ W2), split-K'=3*2048 ----------------
__global__ __launch_bounds__(256)
void gemm2_kernel(const unsigned short* __restrict__ actS,
                  const unsigned short* __restrict__ W2sT,
                  const int* __restrict__ offsets,
                  const int* __restrict__ token_ids,
                  const float* __restrict__ gates,
                  float* __restrict__ out) {
  int e = blockIdx.z;
  int off = offsets[e];
  int cnt = offsets[e+1] - off;
  int r0 = blockIdx.x * 128;
  if (r0 >= cnt) return;
  int c0 = blockIdx.y * 128;

  __shared__ unsigned short As[128*32];
  __shared__ unsigned short Bs[128*32];

  int tid = threadIdx.x;
  int lane = tid & 63, wv = tid >> 6;
  int l15 = lane & 15, lq = lane >> 4;

  f32x4 acc[2][8];
#pragma unroll
  for (int m = 0; m < 2; ++m)
#pragma unroll
    for (int n = 0; n < 8; ++n) acc[m][n] = f32x4{0.f, 0.f, 0.f, 0.f};

  const unsigned short* w2e = W2sT + (size_t)e * 1024 * 4096;

  int oa0 = wv*1024 + lane*16;
  int oa1 = 4096 + oa0;
  int rowA0 = oa0 >> 6, cbA0 = (oa0 & 63) >> 1;
  int rowA1 = oa1 >> 6, cbA1 = (oa1 & 63) >> 1;
  int gpA0 = off + r0 + rowA0; if (gpA0 > TOTAL-1) gpA0 = TOTAL-1;
  int gpA1 = off + r0 + rowA1; if (gpA1 > TOTAL-1) gpA1 = TOTAL-1;
  int colB0 = oa0 >> 6, kbB0 = (oa0 & 63) >> 1;
  int colB1 = oa1 >> 6, kbB1 = (oa1 & 63) >> 1;

  for (int ks = 0; ks < 192; ++ks) {
    int s  = ks >> 6;
    int k0 = (ks & 63) << 5;
    int acol = ((s == 1) ? IDIM : 0) + k0;
    int bk   = ((s == 2) ? IDIM : 0) + k0;

    lds_load16(actS + (size_t)gpA0*4096 + acol + cbA0, (unsigned short*)((char*)As + wv*1024));
    lds_load16(actS + (size_t)gpA1*4096 + acol + cbA1, (unsigned short*)((char*)As + 4096 + wv*1024));
    lds_load16(w2e + (size_t)(c0 + colB0)*4096 + bk + kbB0, (unsigned short*)((char*)Bs + wv*1024));
    lds_load16(w2e + (size_t)(c0 + colB1)*4096 + bk + kbB1, (unsigned short*)((char*)Bs + 4096 + wv*1024));
    __syncthreads();

    bf16x8 af[2], bfr[8];
#pragma unroll
    for (int m = 0; m < 2; ++m)
      af[m] = *reinterpret_cast<const bf16x8*>(&As[(wv*32 + m*16 + l15)*32 + lq*8]);
#pragma unroll
    for (int n = 0; n < 8; ++n)
      bfr[n] = *reinterpret_cast<const bf16x8*>(&Bs[(n*16 + l15)*32 + lq*8]);
#pragma unroll
    for (int m = 0; m < 2; ++m)
#pragma unroll
      for (int n = 0; n < 8; ++n)
        acc[m][n] = __builtin_amdgcn_mfma_f32_16x16x32_bf16(af[m], bfr[n], acc[m][n], 0, 0, 0);
    __syncthreads();
  }

#pragma unroll
  for (int m = 0; m < 2; ++m) {
#pragma unroll
    for (int rr = 0; rr < 4; ++rr) {
      int lrow = r0 + wv*32 + m*16 + lq*4 + rr;
      if (lrow < cnt) {
        int pos = off + lrow;
        int t = token_ids[pos];
        float w = gates[pos];
        float* orow = out + (size_t)t * HDIM;
#pragma unroll
        for (int n = 0; n < 8; ++n)
          atomicAdd(&orow[c0 + n*16 + l15], w * acc[m][n][rr]);
      }
    }
  }
}

extern "C" void kernel_launch(void* const* d_in, const int* in_sizes, int n_in,
                              void* d_out, int out_size, void* d_ws, size_t ws_size,
                              hipStream_t stream) {
  (void)in_sizes; (void)n_in;
  const float* x  = (const float*)d_in[0];
  const float* Wr = (const float*)d_in[1];
  const float* W1 = (const float*)d_in[2];
  const float* W2 = (const float*)d_in[3];
  float* out = (float*)d_out;

  char* ws = (char*)d_ws;
  int*   counts    = (int*)(ws + 0);
  int*   offsets   = (int*)(ws + 64);
  int*   cursor    = (int*)(ws + 128);
  int*   sel       = (int*)(ws + 4096);
  float* selw      = (float*)(ws + 4096 + 65536);
  int*   token_ids = (int*)(ws + 4096 + 2*65536);
  float* gates     = (float*)(ws + 4096 + 3*65536);
  const size_t XS_OFF   = 266240ULL;
  const size_t W1T_OFF  = XS_OFF  + 33554432ULL;      // Xs:   8192*2048*2   = 32 MB
  const size_t W2T_OFF  = W1T_OFF + 134217728ULL;     // W1sT: 8*4096*2048*2 = 128 MB
  const size_t ACT_OFF  = W2T_OFF + 67108864ULL;      // W2sT: 8*1024*4096*2 = 64 MB
  const size_t REQUIRED = ACT_OFF + 134217728ULL;     // actS: 16384*4096*2  = 128 MB => ~352 MB
  unsigned short* Xs   = (unsigned short*)(ws + XS_OFF);
  unsigned short* W1sT = (unsigned short*)(ws + W1T_OFF);
  unsigned short* W2sT = (unsigned short*)(ws + W2T_OFF);
  unsigned short* actS = (unsigned short*)(ws + ACT_OFF);

  hipMemsetAsync(d_out, 0, (size_t)out_size * sizeof(float), stream);
  if (ws_size < REQUIRED) return;  // all-zero output => ws budget too small; restructure next round

  hipMemsetAsync(counts, 0, 64, stream);
  router_kernel<<<NTOK/4, 256, 0, stream>>>(x, Wr, sel, selw, counts);
  prefix_kernel<<<1, 64, 0, stream>>>(counts, offsets, cursor);
  scatter_kernel<<<NTOK/256, 256, 0, stream>>>(sel, selw, cursor, token_ids, gates);
  xsplit_kernel<<<NTOK, 256, 0, stream>>>(x, Xs);
  split_transpose_kernel<<<dim3(64, 16, NEXP), 256, 0, stream>>>(W1, W1sT, 1024, 4096);
  split_transpose_kernel<<<dim3(16, 32, NEXP), 256, 0, stream>>>(W2, W2sT, 2048, 1024);
  gemm1_kernel<<<dim3(64, 32, NEXP), 256, 0, stream>>>(Xs, W1sT, actS, offsets, token_ids);
  gemm2_kernel<<<dim3(64, 8, NEXP), 256, 0, stream>>>(actS, W2sT, offsets, token_ids, gates, out);
}

// Round 5
// 1835.636 us; speedup vs baseline: 1.0818x; 1.0818x over previous
//
#include <hip/hip_runtime.h>
#include <hip/hip_bf16.h>

#define NTOK   8192
#define HDIM   1024
#define NEXP   8
#define IDIM   2048
#define TOTAL  (NTOK*2)

typedef short bf16x8 __attribute__((ext_vector_type(8)));
typedef float f32x4  __attribute__((ext_vector_type(4)));

__device__ __forceinline__ unsigned short f2bf(float f) {
  __hip_bfloat16 h = __float2bfloat16(f);
  return *reinterpret_cast<unsigned short*>(&h);
}
__device__ __forceinline__ float bf2f(unsigned short u) {
  __hip_bfloat16 h = *reinterpret_cast<__hip_bfloat16*>(&u);
  return __bfloat162float(h);
}

// async global->LDS, 16B/lane. LDS base wave-uniform; HW writes base + lane*16.
// Global source address is per-lane (token gather + swizzle folded into source).
__device__ __forceinline__ void lds_load16(const unsigned short* gsrc, unsigned short* lds_base_uniform) {
  __builtin_amdgcn_global_load_lds(
      (const __attribute__((address_space(1))) unsigned int*)gsrc,
      (__attribute__((address_space(3))) unsigned int*)lds_base_uniform,
      16, 0, 0);
}

// ---------------- router: one wave per token ----------------
__global__ void router_kernel(const float* __restrict__ x, const float* __restrict__ Wr,
                              int* __restrict__ sel, float* __restrict__ selw,
                              int* __restrict__ counts) {
  int t = blockIdx.x * 4 + (threadIdx.x >> 6);
  int lane = threadIdx.x & 63;
  float acc[NEXP];
#pragma unroll
  for (int e = 0; e < NEXP; ++e) acc[e] = 0.f;
  const float* xr = x + (size_t)t * HDIM;
  for (int h = lane; h < HDIM; h += 64) {
    float xv = xr[h];
    const float* wr = Wr + h * NEXP;
#pragma unroll
    for (int e = 0; e < NEXP; ++e) acc[e] += xv * wr[e];
  }
#pragma unroll
  for (int off = 32; off > 0; off >>= 1) {
#pragma unroll
    for (int e = 0; e < NEXP; ++e) acc[e] += __shfl_xor(acc[e], off, 64);
  }
  if (lane == 0) {
    int i0 = 0; float v0 = acc[0];
#pragma unroll
    for (int e = 1; e < NEXP; ++e) if (acc[e] > v0) { v0 = acc[e]; i0 = e; }
    int i1 = -1; float v1 = -1e30f;
#pragma unroll
    for (int e = 0; e < NEXP; ++e) if (e != i0 && acc[e] > v1) { v1 = acc[e]; i1 = e; }
    float e1 = expf(v1 - v0);
    float w0 = 1.f / (1.f + e1);
    float w1 = e1 / (1.f + e1);
    sel[t*2] = i0; sel[t*2+1] = i1;
    selw[t*2] = w0; selw[t*2+1] = w1;
    atomicAdd(&counts[i0], 1);
    atomicAdd(&counts[i1], 1);
  }
}

__global__ void prefix_kernel(const int* __restrict__ counts, int* __restrict__ offsets,
                              int* __restrict__ cursor) {
  if (threadIdx.x == 0) {
    int s = 0;
    for (int e = 0; e < NEXP; ++e) { offsets[e] = s; cursor[e] = s; s += counts[e]; }
    offsets[NEXP] = s;
  }
}

__global__ void scatter_kernel(const int* __restrict__ sel, const float* __restrict__ selw,
                               int* __restrict__ cursor, int* __restrict__ token_ids,
                               float* __restrict__ gates) {
  int t = blockIdx.x * 256 + threadIdx.x;
  if (t >= NTOK) return;
#pragma unroll
  for (int k = 0; k < 2; ++k) {
    int e = sel[t*2+k];
    int p = atomicAdd(&cursor[e], 1);
    token_ids[p] = t;
    gates[p] = selw[t*2+k];
  }
}

// x [NTOK][1024] fp32 -> Xs [NTOK][2048] bf16 (hi 0..1023 | lo 1024..2047)
__global__ void xsplit_kernel(const float* __restrict__ x, unsigned short* __restrict__ Xs) {
  int t = blockIdx.x;
  const float4* src = reinterpret_cast<const float4*>(x + (size_t)t * HDIM);
  float4 v = src[threadIdx.x];
  unsigned short h0 = f2bf(v.x), h1 = f2bf(v.y), h2 = f2bf(v.z), h3 = f2bf(v.w);
  ushort4 hi = { h0, h1, h2, h3 };
  ushort4 lo = { f2bf(v.x - bf2f(h0)), f2bf(v.y - bf2f(h1)),
                 f2bf(v.z - bf2f(h2)), f2bf(v.w - bf2f(h3)) };
  *reinterpret_cast<ushort4*>(Xs + (size_t)t*2*HDIM + threadIdx.x*4) = hi;
  *reinterpret_cast<ushort4*>(Xs + (size_t)t*2*HDIM + HDIM + threadIdx.x*4) = lo;
}

// W [E][R][C] fp32 -> WT [E][C][2R] bf16, WT[e][c][r]=hi(W[e][r][c]), WT[e][c][R+r]=lo
__global__ void split_transpose_kernel(const float* __restrict__ W, unsigned short* __restrict__ WT,
                                       int R, int C) {
  int e = blockIdx.z;
  int c0 = blockIdx.x * 64, r0 = blockIdx.y * 64;
  __shared__ unsigned short hiT[64][65];
  __shared__ unsigned short loT[64][65];
  int tx = threadIdx.x & 63, ty = threadIdx.x >> 6;
  const float* src = W + ((size_t)e * R + r0) * C + c0;
#pragma unroll
  for (int rr = 0; rr < 16; ++rr) {
    int r_l = ty * 16 + rr;
    float v = src[(size_t)r_l * C + tx];
    unsigned short h = f2bf(v);
    hiT[tx][r_l] = h;
    loT[tx][r_l] = f2bf(v - bf2f(h));
  }
  __syncthreads();
  unsigned short* dst = WT + ((size_t)e * C + c0) * (size_t)(2*R) + r0;
#pragma unroll
  for (int ww = 0; ww < 16; ++ww) {
    int c_l = ty * 16 + ww;
    dst[(size_t)c_l * (2*R) + tx]     = hiT[c_l][tx];
    dst[(size_t)c_l * (2*R) + R + tx] = loT[c_l][tx];
  }
}

// ---------------- GEMM1: act = silu(Xs@W1g) * (Xs@W1u), split-K'=3*1024, BK=64 ----------------
// LDS rows are 64 elems (128B); 16B granule g of row r holds global granule g^(r&7).
__global__ __launch_bounds__(256)
void gemm1_kernel(const unsigned short* __restrict__ Xs,
                  const unsigned short* __restrict__ W1sT,
                  unsigned short* __restrict__ actS,
                  const int* __restrict__ offsets,
                  const int* __restrict__ token_ids) {
  int e = blockIdx.z;
  int off = offsets[e];
  int cnt = offsets[e+1] - off;
  int r0 = blockIdx.x * 128;
  if (r0 >= cnt) return;
  int j0 = blockIdx.y * 64;

  __shared__ unsigned short As[128*64];   // 16KB
  __shared__ unsigned short Bg[64*64];    // 8KB
  __shared__ unsigned short Bu[64*64];    // 8KB

  int tid = threadIdx.x;
  int lane = tid & 63, wv = tid >> 6;
  int l15 = lane & 15, lq = lane >> 4;
  int lr = lane >> 3;         // row within 8-row issue
  int g  = lane & 7;          // dest granule

  const unsigned short* w1e = W1sT + (size_t)e * 4096 * 2048;

  // staging pointers, swizzle folded into SOURCE address (LDS dest stays linear)
  const unsigned short* srcA[4]; unsigned short* dstA[4];
#pragma unroll
  for (int i = 0; i < 4; ++i) {
    int rowt = wv*32 + i*8 + lr;
    int gp = off + r0 + rowt; if (gp > TOTAL-1) gp = TOTAL-1;
    int tok = token_ids[gp];
    int sg = g ^ (rowt & 7);
    srcA[i] = Xs + (size_t)tok*2048 + sg*8;
    dstA[i] = As + wv*2048 + i*512;
  }
  const unsigned short* srcBg[2]; const unsigned short* srcBu[2];
  unsigned short* dstBg[2]; unsigned short* dstBu[2];
#pragma unroll
  for (int i = 0; i < 2; ++i) {
    int rowt = wv*16 + i*8 + lr;
    int sg = g ^ (rowt & 7);
    srcBg[i] = w1e + (size_t)(j0 + rowt)*2048 + sg*8;
    srcBu[i] = w1e + (size_t)(IDIM + j0 + rowt)*2048 + sg*8;
    dstBg[i] = Bg + wv*1024 + i*512;
    dstBu[i] = Bu + wv*1024 + i*512;
  }

  f32x4 accg[2][4], accu[2][4];
#pragma unroll
  for (int m = 0; m < 2; ++m)
#pragma unroll
    for (int n = 0; n < 4; ++n) {
      accg[m][n] = f32x4{0.f, 0.f, 0.f, 0.f};
      accu[m][n] = f32x4{0.f, 0.f, 0.f, 0.f};
    }

  for (int ks = 0; ks < 48; ++ks) {
    int s  = ks >> 4;
    int k0 = (ks & 15) << 6;
    int aoff = ((s == 1) ? HDIM : 0) + k0;   // pass1 reads A-lo
    int boff = ((s == 2) ? HDIM : 0) + k0;   // pass2 reads B-lo

#pragma unroll
    for (int i = 0; i < 4; ++i) lds_load16(srcA[i] + aoff, dstA[i]);
#pragma unroll
    for (int i = 0; i < 2; ++i) {
      lds_load16(srcBg[i] + boff, dstBg[i]);
      lds_load16(srcBu[i] + boff, dstBu[i]);
    }
    __syncthreads();

#pragma unroll
    for (int kk = 0; kk < 2; ++kk) {
      int gg = ((kk*4 + lq) ^ (l15 & 7)) * 8;   // de-swizzled granule offset (elems)
      bf16x8 af[2], bgf[4], buf2[4];
#pragma unroll
      for (int m = 0; m < 2; ++m)
        af[m] = *reinterpret_cast<const bf16x8*>(&As[(wv*32 + m*16 + l15)*64 + gg]);
#pragma unroll
      for (int n = 0; n < 4; ++n) {
        bgf[n]  = *reinterpret_cast<const bf16x8*>(&Bg[(n*16 + l15)*64 + gg]);
        buf2[n] = *reinterpret_cast<const bf16x8*>(&Bu[(n*16 + l15)*64 + gg]);
      }
#pragma unroll
      for (int m = 0; m < 2; ++m)
#pragma unroll
        for (int n = 0; n < 4; ++n) {
          accg[m][n] = __builtin_amdgcn_mfma_f32_16x16x32_bf16(af[m], bgf[n], accg[m][n], 0, 0, 0);
          accu[m][n] = __builtin_amdgcn_mfma_f32_16x16x32_bf16(af[m], buf2[n], accu[m][n], 0, 0, 0);
        }
    }
    __syncthreads();
  }

#pragma unroll
  for (int m = 0; m < 2; ++m) {
#pragma unroll
    for (int rr = 0; rr < 4; ++rr) {
      int lrow = r0 + wv*32 + m*16 + lq*4 + rr;
      if (lrow < cnt) {
        size_t prow = (size_t)(off + lrow);
#pragma unroll
        for (int n = 0; n < 4; ++n) {
          float gte = accg[m][n][rr], u = accu[m][n][rr];
          float a = (gte / (1.f + expf(-gte))) * u;   // silu(g)*u
          unsigned short hh = f2bf(a);
          unsigned short ll = f2bf(a - bf2f(hh));
          int col = j0 + n*16 + l15;
          actS[prow*4096 + col]        = hh;
          actS[prow*4096 + IDIM + col] = ll;
        }
      }
    }
  }
}

// ---------------- GEMM2: out += g * (act @ W2), split-K'=3*2048, BK=64 ----------------
__global__ __launch_bounds__(256)
void gemm2_kernel(const unsigned short* __restrict__ actS,
                  const unsigned short* __restrict__ W2sT,
                  const int* __restrict__ offsets,
                  const int* __restrict__ token_ids,
                  const float* __restrict__ gates,
                  float* __restrict__ out) {
  int e = blockIdx.z;
  int off = offsets[e];
  int cnt = offsets[e+1] - off;
  int r0 = blockIdx.x * 128;
  if (r0 >= cnt) return;
  int c0 = blockIdx.y * 128;

  __shared__ unsigned short As[128*64];   // 16KB
  __shared__ unsigned short Bs[128*64];   // 16KB

  int tid = threadIdx.x;
  int lane = tid & 63, wv = tid >> 6;
  int l15 = lane & 15, lq = lane >> 4;
  int lr = lane >> 3;
  int g  = lane & 7;

  const unsigned short* w2e = W2sT + (size_t)e * 1024 * 4096;

  const unsigned short* srcA[4]; unsigned short* dstA[4];
  const unsigned short* srcB[4]; unsigned short* dstB[4];
#pragma unroll
  for (int i = 0; i < 4; ++i) {
    int rowt = wv*32 + i*8 + lr;
    int gp = off + r0 + rowt; if (gp > TOTAL-1) gp = TOTAL-1;
    int sg = g ^ (rowt & 7);
    srcA[i] = actS + (size_t)gp*4096 + sg*8;
    dstA[i] = As + wv*2048 + i*512;
    srcB[i] = w2e + (size_t)(c0 + rowt)*4096 + sg*8;
    dstB[i] = Bs + wv*2048 + i*512;
  }

  f32x4 acc[2][8];
#pragma unroll
  for (int m = 0; m < 2; ++m)
#pragma unroll
    for (int n = 0; n < 8; ++n) acc[m][n] = f32x4{0.f, 0.f, 0.f, 0.f};

  for (int ks = 0; ks < 96; ++ks) {
    int s  = ks >> 5;
    int k0 = (ks & 31) << 6;
    int aoff = ((s == 1) ? IDIM : 0) + k0;
    int boff = ((s == 2) ? IDIM : 0) + k0;

#pragma unroll
    for (int i = 0; i < 4; ++i) {
      lds_load16(srcA[i] + aoff, dstA[i]);
      lds_load16(srcB[i] + boff, dstB[i]);
    }
    __syncthreads();

#pragma unroll
    for (int kk = 0; kk < 2; ++kk) {
      int gg = ((kk*4 + lq) ^ (l15 & 7)) * 8;
      bf16x8 af[2], bfr[8];
#pragma unroll
      for (int m = 0; m < 2; ++m)
        af[m] = *reinterpret_cast<const bf16x8*>(&As[(wv*32 + m*16 + l15)*64 + gg]);
#pragma unroll
      for (int n = 0; n < 8; ++n)
        bfr[n] = *reinterpret_cast<const bf16x8*>(&Bs[(n*16 + l15)*64 + gg]);
#pragma unroll
      for (int m = 0; m < 2; ++m)
#pragma unroll
        for (int n = 0; n < 8; ++n)
          acc[m][n] = __builtin_amdgcn_mfma_f32_16x16x32_bf16(af[m], bfr[n], acc[m][n], 0, 0, 0);
    }
    __syncthreads();
  }

#pragma unroll
  for (int m = 0; m < 2; ++m) {
#pragma unroll
    for (int rr = 0; rr < 4; ++rr) {
      int lrow = r0 + wv*32 + m*16 + lq*4 + rr;
      if (lrow < cnt) {
        int pos = off + lrow;
        int t = token_ids[pos];
        float w = gates[pos];
        float* orow = out + (size_t)t * HDIM;
#pragma unroll
        for (int n = 0; n < 8; ++n)
          atomicAdd(&orow[c0 + n*16 + l15], w * acc[m][n][rr]);
      }
    }
  }
}

extern "C" void kernel_launch(void* const* d_in, const int* in_sizes, int n_in,
                              void* d_out, int out_size, void* d_ws, size_t ws_size,
                              hipStream_t stream) {
  (void)in_sizes; (void)n_in;
  const float* x  = (const float*)d_in[0];
  const float* Wr = (const float*)d_in[1];
  const float* W1 = (const float*)d_in[2];
  const float* W2 = (const float*)d_in[3];
  float* out = (float*)d_out;

  char* ws = (char*)d_ws;
  int*   counts    = (int*)(ws + 0);
  int*   offsets   = (int*)(ws + 64);
  int*   cursor    = (int*)(ws + 128);
  int*   sel       = (int*)(ws + 4096);
  float* selw      = (float*)(ws + 4096 + 65536);
  int*   token_ids = (int*)(ws + 4096 + 2*65536);
  float* gates     = (float*)(ws + 4096 + 3*65536);
  const size_t XS_OFF   = 266240ULL;
  const size_t W1T_OFF  = XS_OFF  + 33554432ULL;      // Xs:   8192*2048*2   = 32 MB
  const size_t W2T_OFF  = W1T_OFF + 134217728ULL;     // W1sT: 8*4096*2048*2 = 128 MB
  const size_t ACT_OFF  = W2T_OFF + 67108864ULL;      // W2sT: 8*1024*4096*2 = 64 MB
  const size_t REQUIRED = ACT_OFF + 134217728ULL;     // actS: 16384*4096*2  = 128 MB => ~352 MB
  unsigned short* Xs   = (unsigned short*)(ws + XS_OFF);
  unsigned short* W1sT = (unsigned short*)(ws + W1T_OFF);
  unsigned short* W2sT = (unsigned short*)(ws + W2T_OFF);
  unsigned short* actS = (unsigned short*)(ws + ACT_OFF);

  hipMemsetAsync(d_out, 0, (size_t)out_size * sizeof(float), stream);
  if (ws_size < REQUIRED) return;

  hipMemsetAsync(counts, 0, 64, stream);
  router_kernel<<<NTOK/4, 256, 0, stream>>>(x, Wr, sel, selw, counts);
  prefix_kernel<<<1, 64, 0, stream>>>(counts, offsets, cursor);
  scatter_kernel<<<NTOK/256, 256, 0, stream>>>(sel, selw, cursor, token_ids, gates);
  xsplit_kernel<<<NTOK, 256, 0, stream>>>(x, Xs);
  split_transpose_kernel<<<dim3(64, 16, NEXP), 256, 0, stream>>>(W1, W1sT, 1024, 4096);
  split_transpose_kernel<<<dim3(16, 32, NEXP), 256, 0, stream>>>(W2, W2sT, 2048, 1024);
  gemm1_kernel<<<dim3(64, 32, NEXP), 256, 0, stream>>>(Xs, W1sT, actS, offsets, token_ids);
  gemm2_kernel<<<dim3(64, 8, NEXP), 256, 0, stream>>>(actS, W2sT, offsets, token_ids, gates, out);
}

// Round 7
// 1660.051 us; speedup vs baseline: 1.1962x; 1.1058x over previous
//
#include <hip/hip_runtime.h>
#include <hip/hip_bf16.h>

#define NTOK   8192
#define HDIM   1024
#define NEXP   8
#define IDIM   2048
#define TOTAL  (NTOK*2)

typedef short bf16x8 __attribute__((ext_vector_type(8)));
typedef float f32x4  __attribute__((ext_vector_type(4)));

__device__ __forceinline__ unsigned short f2bf(float f) {
  __hip_bfloat16 h = __float2bfloat16(f);
  return *reinterpret_cast<unsigned short*>(&h);
}
__device__ __forceinline__ float bf2f(unsigned short u) {
  __hip_bfloat16 h = *reinterpret_cast<__hip_bfloat16*>(&u);
  return __bfloat162float(h);
}

// async global->LDS, 16B/lane. LDS base wave-uniform; HW writes base + lane*16.
// Global source address is per-lane (token gather + swizzle folded into source).
__device__ __forceinline__ void lds_load16(const unsigned short* gsrc, unsigned short* lds_base_uniform) {
  __builtin_amdgcn_global_load_lds(
      (const __attribute__((address_space(1))) unsigned int*)gsrc,
      (__attribute__((address_space(3))) unsigned int*)lds_base_uniform,
      16, 0, 0);
}

// ---------------- router: one wave per token ----------------
__global__ void router_kernel(const float* __restrict__ x, const float* __restrict__ Wr,
                              int* __restrict__ sel, float* __restrict__ selw,
                              int* __restrict__ counts) {
  int t = blockIdx.x * 4 + (threadIdx.x >> 6);
  int lane = threadIdx.x & 63;
  float acc[NEXP];
#pragma unroll
  for (int e = 0; e < NEXP; ++e) acc[e] = 0.f;
  const float* xr = x + (size_t)t * HDIM;
  for (int h = lane; h < HDIM; h += 64) {
    float xv = xr[h];
    const float* wr = Wr + h * NEXP;
#pragma unroll
    for (int e = 0; e < NEXP; ++e) acc[e] += xv * wr[e];
  }
#pragma unroll
  for (int off = 32; off > 0; off >>= 1) {
#pragma unroll
    for (int e = 0; e < NEXP; ++e) acc[e] += __shfl_xor(acc[e], off, 64);
  }
  if (lane == 0) {
    int i0 = 0; float v0 = acc[0];
#pragma unroll
    for (int e = 1; e < NEXP; ++e) if (acc[e] > v0) { v0 = acc[e]; i0 = e; }
    int i1 = -1; float v1 = -1e30f;
#pragma unroll
    for (int e = 0; e < NEXP; ++e) if (e != i0 && acc[e] > v1) { v1 = acc[e]; i1 = e; }
    float e1 = expf(v1 - v0);
    float w0 = 1.f / (1.f + e1);
    float w1 = e1 / (1.f + e1);
    sel[t*2] = i0; sel[t*2+1] = i1;
    selw[t*2] = w0; selw[t*2+1] = w1;
    atomicAdd(&counts[i0], 1);
    atomicAdd(&counts[i1], 1);
  }
}

__global__ void prefix_kernel(const int* __restrict__ counts, int* __restrict__ offsets,
                              int* __restrict__ cursor) {
  if (threadIdx.x == 0) {
    int s = 0;
    for (int e = 0; e < NEXP; ++e) { offsets[e] = s; cursor[e] = s; s += counts[e]; }
    offsets[NEXP] = s;
  }
}

__global__ void scatter_kernel(const int* __restrict__ sel, const float* __restrict__ selw,
                               int* __restrict__ cursor, int* __restrict__ token_ids,
                               float* __restrict__ gates) {
  int t = blockIdx.x * 256 + threadIdx.x;
  if (t >= NTOK) return;
#pragma unroll
  for (int k = 0; k < 2; ++k) {
    int e = sel[t*2+k];
    int p = atomicAdd(&cursor[e], 1);
    token_ids[p] = t;
    gates[p] = selw[t*2+k];
  }
}

// x [NTOK][1024] fp32 -> Xs [NTOK][2048] bf16 (hi 0..1023 | lo 1024..2047)
__global__ void xsplit_kernel(const float* __restrict__ x, unsigned short* __restrict__ Xs) {
  int t = blockIdx.x;
  const float4* src = reinterpret_cast<const float4*>(x + (size_t)t * HDIM);
  float4 v = src[threadIdx.x];
  unsigned short h0 = f2bf(v.x), h1 = f2bf(v.y), h2 = f2bf(v.z), h3 = f2bf(v.w);
  ushort4 hi = { h0, h1, h2, h3 };
  ushort4 lo = { f2bf(v.x - bf2f(h0)), f2bf(v.y - bf2f(h1)),
                 f2bf(v.z - bf2f(h2)), f2bf(v.w - bf2f(h3)) };
  *reinterpret_cast<ushort4*>(Xs + (size_t)t*2*HDIM + threadIdx.x*4) = hi;
  *reinterpret_cast<ushort4*>(Xs + (size_t)t*2*HDIM + HDIM + threadIdx.x*4) = lo;
}

// W [E][R][C] fp32 -> WT [E][C][2R] bf16, WT[e][c][r]=hi(W[e][r][c]), WT[e][c][R+r]=lo
__global__ void split_transpose_kernel(const float* __restrict__ W, unsigned short* __restrict__ WT,
                                       int R, int C) {
  int e = blockIdx.z;
  int c0 = blockIdx.x * 64, r0 = blockIdx.y * 64;
  __shared__ unsigned short hiT[64][65];
  __shared__ unsigned short loT[64][65];
  int tx = threadIdx.x & 63, ty = threadIdx.x >> 6;
  const float* src = W + ((size_t)e * R + r0) * C + c0;
#pragma unroll
  for (int rr = 0; rr < 16; ++rr) {
    int r_l = ty * 16 + rr;
    float v = src[(size_t)r_l * C + tx];
    unsigned short h = f2bf(v);
    hiT[tx][r_l] = h;
    loT[tx][r_l] = f2bf(v - bf2f(h));
  }
  __syncthreads();
  unsigned short* dst = WT + ((size_t)e * C + c0) * (size_t)(2*R) + r0;
#pragma unroll
  for (int ww = 0; ww < 16; ++ww) {
    int c_l = ty * 16 + ww;
    dst[(size_t)c_l * (2*R) + tx]     = hiT[c_l][tx];
    dst[(size_t)c_l * (2*R) + R + tx] = loT[c_l][tx];
  }
}

// ---------------- GEMM1: act = silu(Xs@W1g) * (Xs@W1u), split-K'=3*1024, BK=64 ----------------
// Block tile: 128 rows x 128 j-cols (gate AND up). Wave tile: 64 rows x 64 cols x 2 types.
// LDS rows are 64 elems (128B); 16B granule slot g of row r holds global granule g^(r&7).
__global__ __launch_bounds__(256, 2)
void gemm1_kernel(const unsigned short* __restrict__ Xs,
                  const unsigned short* __restrict__ W1sT,
                  unsigned short* __restrict__ actS,
                  const int* __restrict__ offsets,
                  const int* __restrict__ token_ids) {
  int e = blockIdx.z;
  int off = offsets[e];
  int cnt = offsets[e+1] - off;
  int r0 = blockIdx.x * 128;
  if (r0 >= cnt) return;
  int j0 = blockIdx.y * 128;

  __shared__ unsigned short As[128*64];   // 16KB
  __shared__ unsigned short Bg[128*64];   // 16KB
  __shared__ unsigned short Bu[128*64];   // 16KB

  int tid = threadIdx.x;
  int lane = tid & 63, wv = tid >> 6;
  int l15 = lane & 15, lq = lane >> 4;
  int lr = lane >> 3;         // row within 8-row issue
  int g  = lane & 7;          // dest granule
  int wr = wv >> 1;           // wave row-half (64 rows)
  int wc = wv & 1;            // wave col-half (64 cols)

  const unsigned short* w1e = W1sT + (size_t)e * 4096 * 2048;

  // staging pointers, swizzle folded into SOURCE address (LDS dest stays linear)
  const unsigned short* srcA[4]; unsigned short* dstA[4];
  const unsigned short* srcBg[4]; const unsigned short* srcBu[4];
  unsigned short* dstBg[4]; unsigned short* dstBu[4];
#pragma unroll
  for (int i = 0; i < 4; ++i) {
    int rowt = wv*32 + i*8 + lr;
    int gp = off + r0 + rowt; if (gp > TOTAL-1) gp = TOTAL-1;
    int tok = token_ids[gp];
    int sg = g ^ (rowt & 7);
    srcA[i] = Xs + (size_t)tok*2048 + sg*8;
    dstA[i] = As + wv*2048 + i*512;
    srcBg[i] = w1e + (size_t)(j0 + rowt)*2048 + sg*8;
    srcBu[i] = w1e + (size_t)(IDIM + j0 + rowt)*2048 + sg*8;
    dstBg[i] = Bg + wv*2048 + i*512;
    dstBu[i] = Bu + wv*2048 + i*512;
  }

  f32x4 accg[4][4], accu[4][4];
#pragma unroll
  for (int m = 0; m < 4; ++m)
#pragma unroll
    for (int n = 0; n < 4; ++n) {
      accg[m][n] = f32x4{0.f, 0.f, 0.f, 0.f};
      accu[m][n] = f32x4{0.f, 0.f, 0.f, 0.f};
    }

  for (int ks = 0; ks < 48; ++ks) {
    int s  = ks >> 4;
    int k0 = (ks & 15) << 6;
    int aoff = ((s == 1) ? HDIM : 0) + k0;   // pass1 reads A-lo
    int boff = ((s == 2) ? HDIM : 0) + k0;   // pass2 reads B-lo

#pragma unroll
    for (int i = 0; i < 4; ++i) lds_load16(srcA[i] + aoff, dstA[i]);
#pragma unroll
    for (int i = 0; i < 4; ++i) {
      lds_load16(srcBg[i] + boff, dstBg[i]);
      lds_load16(srcBu[i] + boff, dstBu[i]);
    }
    __syncthreads();

#pragma unroll
    for (int kk = 0; kk < 2; ++kk) {
      int gg = ((kk*4 + lq) ^ (l15 & 7)) * 8;   // de-swizzled granule offset (elems)
      bf16x8 af[4], bgf[4], buf2[4];
#pragma unroll
      for (int m = 0; m < 4; ++m)
        af[m] = *reinterpret_cast<const bf16x8*>(&As[(wr*64 + m*16 + l15)*64 + gg]);
#pragma unroll
      for (int n = 0; n < 4; ++n) {
        bgf[n]  = *reinterpret_cast<const bf16x8*>(&Bg[(wc*64 + n*16 + l15)*64 + gg]);
        buf2[n] = *reinterpret_cast<const bf16x8*>(&Bu[(wc*64 + n*16 + l15)*64 + gg]);
      }
#pragma unroll
      for (int m = 0; m < 4; ++m)
#pragma unroll
        for (int n = 0; n < 4; ++n) {
          accg[m][n] = __builtin_amdgcn_mfma_f32_16x16x32_bf16(af[m], bgf[n], accg[m][n], 0, 0, 0);
          accu[m][n] = __builtin_amdgcn_mfma_f32_16x16x32_bf16(af[m], buf2[n], accu[m][n], 0, 0, 0);
        }
    }
    __syncthreads();
  }

#pragma unroll
  for (int m = 0; m < 4; ++m) {
#pragma unroll
    for (int rr = 0; rr < 4; ++rr) {
      int lrow = r0 + wr*64 + m*16 + lq*4 + rr;
      if (lrow < cnt) {
        size_t prow = (size_t)(off + lrow);
#pragma unroll
        for (int n = 0; n < 4; ++n) {
          float gte = accg[m][n][rr], u = accu[m][n][rr];
          float a = (gte / (1.f + expf(-gte))) * u;   // silu(g)*u
          unsigned short hh = f2bf(a);
          unsigned short ll = f2bf(a - bf2f(hh));
          int col = j0 + wc*64 + n*16 + l15;
          actS[prow*4096 + col]        = hh;
          actS[prow*4096 + IDIM + col] = ll;
        }
      }
    }
  }
}

// ---------------- GEMM2: out += g * (act @ W2), split-K'=3*2048, BK=64 ----------------
// Block tile: 128 rows x 256 cols. Wave tile: 64 rows x 128 cols.
__global__ __launch_bounds__(256, 2)
void gemm2_kernel(const unsigned short* __restrict__ actS,
                  const unsigned short* __restrict__ W2sT,
                  const int* __restrict__ offsets,
                  const int* __restrict__ token_ids,
                  const float* __restrict__ gates,
                  float* __restrict__ out) {
  int e = blockIdx.z;
  int off = offsets[e];
  int cnt = offsets[e+1] - off;
  int r0 = blockIdx.x * 128;
  if (r0 >= cnt) return;
  int c0 = blockIdx.y * 256;

  __shared__ unsigned short As[128*64];   // 16KB
  __shared__ unsigned short Bs[256*64];   // 32KB

  int tid = threadIdx.x;
  int lane = tid & 63, wv = tid >> 6;
  int l15 = lane & 15, lq = lane >> 4;
  int lr = lane >> 3;
  int g  = lane & 7;
  int wr = wv >> 1;           // wave row-half (64 rows)
  int wc = wv & 1;            // wave col-half (128 cols)

  const unsigned short* w2e = W2sT + (size_t)e * 1024 * 4096;

  const unsigned short* srcA[4]; unsigned short* dstA[4];
  const unsigned short* srcB[8]; unsigned short* dstB[8];
#pragma unroll
  for (int i = 0; i < 4; ++i) {
    int rowt = wv*32 + i*8 + lr;
    int gp = off + r0 + rowt; if (gp > TOTAL-1) gp = TOTAL-1;
    int sg = g ^ (rowt & 7);
    srcA[i] = actS + (size_t)gp*4096 + sg*8;
    dstA[i] = As + wv*2048 + i*512;
  }
#pragma unroll
  for (int i = 0; i < 8; ++i) {
    int rowt = wv*64 + i*8 + lr;
    int sg = g ^ (rowt & 7);
    srcB[i] = w2e + (size_t)(c0 + rowt)*4096 + sg*8;
    dstB[i] = Bs + wv*4096 + i*512;
  }

  f32x4 acc[4][8];
#pragma unroll
  for (int m = 0; m < 4; ++m)
#pragma unroll
    for (int n = 0; n < 8; ++n) acc[m][n] = f32x4{0.f, 0.f, 0.f, 0.f};

  for (int ks = 0; ks < 96; ++ks) {
    int s  = ks >> 5;
    int k0 = (ks & 31) << 6;
    int aoff = ((s == 1) ? IDIM : 0) + k0;
    int boff = ((s == 2) ? IDIM : 0) + k0;

#pragma unroll
    for (int i = 0; i < 4; ++i) lds_load16(srcA[i] + aoff, dstA[i]);
#pragma unroll
    for (int i = 0; i < 8; ++i) lds_load16(srcB[i] + boff, dstB[i]);
    __syncthreads();

#pragma unroll
    for (int kk = 0; kk < 2; ++kk) {
      int gg = ((kk*4 + lq) ^ (l15 & 7)) * 8;
      bf16x8 af[4], bfr[8];
#pragma unroll
      for (int m = 0; m < 4; ++m)
        af[m] = *reinterpret_cast<const bf16x8*>(&As[(wr*64 + m*16 + l15)*64 + gg]);
#pragma unroll
      for (int n = 0; n < 8; ++n)
        bfr[n] = *reinterpret_cast<const bf16x8*>(&Bs[(wc*128 + n*16 + l15)*64 + gg]);
#pragma unroll
      for (int m = 0; m < 4; ++m)
#pragma unroll
        for (int n = 0; n < 8; ++n)
          acc[m][n] = __builtin_amdgcn_mfma_f32_16x16x32_bf16(af[m], bfr[n], acc[m][n], 0, 0, 0);
    }
    __syncthreads();
  }

#pragma unroll
  for (int m = 0; m < 4; ++m) {
#pragma unroll
    for (int rr = 0; rr < 4; ++rr) {
      int lrow = r0 + wr*64 + m*16 + lq*4 + rr;
      if (lrow < cnt) {
        int pos = off + lrow;
        int t = token_ids[pos];
        float w = gates[pos];
        float* orow = out + (size_t)t * HDIM;
#pragma unroll
        for (int n = 0; n < 8; ++n)
          atomicAdd(&orow[c0 + wc*128 + n*16 + l15], w * acc[m][n][rr]);
      }
    }
  }
}

extern "C" void kernel_launch(void* const* d_in, const int* in_sizes, int n_in,
                              void* d_out, int out_size, void* d_ws, size_t ws_size,
                              hipStream_t stream) {
  (void)in_sizes; (void)n_in;
  const float* x  = (const float*)d_in[0];
  const float* Wr = (const float*)d_in[1];
  const float* W1 = (const float*)d_in[2];
  const float* W2 = (const float*)d_in[3];
  float* out = (float*)d_out;

  char* ws = (char*)d_ws;
  int*   counts    = (int*)(ws + 0);
  int*   offsets   = (int*)(ws + 64);
  int*   cursor    = (int*)(ws + 128);
  int*   sel       = (int*)(ws + 4096);
  float* selw      = (float*)(ws + 4096 + 65536);
  int*   token_ids = (int*)(ws + 4096 + 2*65536);
  float* gates     = (float*)(ws + 4096 + 3*65536);
  const size_t XS_OFF   = 266240ULL;
  const size_t W1T_OFF  = XS_OFF  + 33554432ULL;      // Xs:   8192*2048*2   = 32 MB
  const size_t W2T_OFF  = W1T_OFF + 134217728ULL;     // W1sT: 8*4096*2048*2 = 128 MB
  const size_t ACT_OFF  = W2T_OFF + 67108864ULL;      // W2sT: 8*1024*4096*2 = 64 MB
  const size_t REQUIRED = ACT_OFF + 134217728ULL;     // actS: 16384*4096*2  = 128 MB => ~352 MB
  unsigned short* Xs   = (unsigned short*)(ws + XS_OFF);
  unsigned short* W1sT = (unsigned short*)(ws + W1T_OFF);
  unsigned short* W2sT = (unsigned short*)(ws + W2T_OFF);
  unsigned short* actS = (unsigned short*)(ws + ACT_OFF);

  hipMemsetAsync(d_out, 0, (size_t)out_size * sizeof(float), stream);
  if (ws_size < REQUIRED) return;

  hipMemsetAsync(counts, 0, 64, stream);
  router_kernel<<<NTOK/4, 256, 0, stream>>>(x, Wr, sel, selw, counts);
  prefix_kernel<<<1, 64, 0, stream>>>(counts, offsets, cursor);
  scatter_kernel<<<NTOK/256, 256, 0, stream>>>(sel, selw, cursor, token_ids, gates);
  xsplit_kernel<<<NTOK, 256, 0, stream>>>(x, Xs);
  split_transpose_kernel<<<dim3(64, 16, NEXP), 256, 0, stream>>>(W1, W1sT, 1024, 4096);
  split_transpose_kernel<<<dim3(16, 32, NEXP), 256, 0, stream>>>(W2, W2sT, 2048, 1024);
  gemm1_kernel<<<dim3(64, 16, NEXP), 256, 0, stream>>>(Xs, W1sT, actS, offsets, token_ids);
  gemm2_kernel<<<dim3(64, 4, NEXP), 256, 0, stream>>>(actS, W2sT, offsets, token_ids, gates, out);
}